// Round 7
// baseline (44.077 us; speedup 1.0000x reference)
//
#include <hip/hip_runtime.h>
#include <cstdint>
#include <climits>

#define GRID_N 16777216
#define N_STEPS 100
#define NCAND (2 * N_STEPS + 1)   // 200 boundary-origin candidates + c0
#define NBLK 2048
#define THREADS 256
#define TTOT (NBLK * THREADS)     // 524288 threads; GRID_N/2 = 16*TTOT float4s
#define SENT 0xFFFFFFFFFFFFFFFFULL  // memset(0xFF) = negative-NaN; sum-of-squares can never produce it

// nan_to_num(psi, nan=0.0, posinf=1.0, neginf=-1.0)
__device__ __forceinline__ float fixv(float v) {
    if (isnan(v)) return 0.0f;
    if (isinf(v)) return v > 0.0f ? 1.0f : -1.0f;
    return v;
}

// psi0*psi0 + psi1*psi1 in strict f32, no FMA contraction (match host semantics)
__device__ __forceinline__ float raw_prob(float a, float b) {
    return __fadd_rn(__fmul_rn(a, a), __fmul_rn(b, b));
}

// x86 cvttss2si semantics: out-of-range or NaN -> INT_MIN (NOT GPU saturation)
__device__ __forceinline__ int host_f2i(float sf) {
    if (!(sf >= -2147483648.0f && sf < 2147483648.0f)) return INT_MIN;
    return (int)sf;
}

__device__ __forceinline__ int wrap_clip(int c, int shift) {
    int r = (int)((unsigned)c + (unsigned)shift);  // int32 wrapping add (XLA/NumPy)
    if (r < 0) r = 0;
    if (r > GRID_N - 1) r = GRID_N - 1;
    return r;
}

__device__ __forceinline__ double pair_prob(float4 v) {
    return (double)raw_prob(fixv(v.x), fixv(v.y)) +
           (double)raw_prob(fixv(v.z), fixv(v.w));
}

__global__ __launch_bounds__(256) void qpe_fused3_kernel(const float* __restrict__ psi,
                                                         const float* __restrict__ noise,
                                                         const float* __restrict__ x,
                                                         const int* __restrict__ c0p,
                                                         unsigned long long* __restrict__ partials_u,
                                                         float* __restrict__ out) {
    const int tid = threadIdx.x;
    const int bid = blockIdx.x;

    const float DXf    = (float)(20.0 / (double)(GRID_N - 1));
    const float TWODXf = (float)(2.0 * (20.0 / (double)(GRID_N - 1)));
    const float DTf    = 0.01f;
    const float SQ2DTf = (float)0.14142135623730950488;  // np.sqrt(0.02) -> f32

    __shared__ double red[256];
    __shared__ int    cand_c[256];
    __shared__ int    cand_next[256];
    __shared__ float  norm_sh;

    // ---- block 0 only: candidate positions; issue psi loads FIRST ----
    // From a boundary b at step t (score==0 there), the next index is
    //   clip(wrap(b, int((noise[t]*sqrt2dt)/DX)))  -- a function of noise only.
    int myc = -1;
    float2 lo = make_float2(0.0f, 0.0f), hi = make_float2(0.0f, 0.0f);
    if (bid == 0 && tid < NCAND) {
        if (tid == NCAND - 1) {
            myc = *c0p;
        } else {
            int t = tid >> 1;
            float n = noise[t];
            // identical fp sequence to a walk step with s==0:
            float move = __fadd_rn(__fmul_rn(0.0f, DTf), __fmul_rn(n, SQ2DTf));
            if (!isfinite(move)) move = 0.0f;
            int shift = host_f2i(__fdiv_rn(move, DXf));
            int b = (tid & 1) ? (GRID_N - 1) : 0;
            myc = wrap_clip(b, shift);
        }
        if (myc > 0 && myc < GRID_N - 1) {
            lo = *(const float2*)(psi + 2 * myc - 2);  // psi[c-1][0..1]
            hi = *(const float2*)(psi + 2 * myc + 2);  // psi[c+1][0..1]
        }
        // pin loads here so the compiler cannot sink them past the sum phase
        asm volatile("" : "+v"(lo.x), "+v"(lo.y), "+v"(hi.x), "+v"(hi.y));
    }

    // ---- every block: sum slice `bid` (bit-identical partition/order to r6) ----
    {
        const float4* psi4 = (const float4*)psi;
        int i = bid * THREADS + tid;
        double a0 = 0.0, a1 = 0.0, a2 = 0.0, a3 = 0.0;
#pragma unroll
        for (int k = 0; k < 4; ++k) {
            float4 v0 = psi4[i];
            float4 v1 = psi4[i + TTOT];
            float4 v2 = psi4[i + 2 * TTOT];
            float4 v3 = psi4[i + 3 * TTOT];
            i += 4 * TTOT;
            a0 += pair_prob(v0);
            a1 += pair_prob(v1);
            a2 += pair_prob(v2);
            a3 += pair_prob(v3);
        }
        double acc = (a0 + a1) + (a2 + a3);
        red[tid] = acc;
        __syncthreads();
        for (int s = 128; s > 0; s >>= 1) {   // fixed-order tree -> deterministic
            if (tid < s) red[tid] += red[tid + s];
            __syncthreads();
        }
        if (tid == 0) {
            // publish: ONE relaxed agent-scope 8B store. The value IS the flag.
            // No RMW (r5's serialization), no acquire/release fences (r4's wbl2/inv).
            double v = red[0];
            unsigned long long u;
            __builtin_memcpy(&u, &v, 8);
            __hip_atomic_store(&partials_u[bid], u, __ATOMIC_RELAXED,
                               __HIP_MEMORY_SCOPE_AGENT);
        }
    }
    if (bid != 0) return;

    // ---- block 0: poll all 2048 partials (sentinel = not yet written) ----
    double myv[NBLK / 256];
#pragma unroll
    for (int k = 0; k < NBLK / 256; ++k) {
        unsigned long long u;
        for (;;) {
            u = __hip_atomic_load(&partials_u[tid + k * 256], __ATOMIC_RELAXED,
                                  __HIP_MEMORY_SCOPE_AGENT);
            if (u != SENT) break;
            __builtin_amdgcn_s_sleep(1);
        }
        __builtin_memcpy(&myv[k], &u, 8);
    }

    // ---- phase B: deterministic fixed-order f64 reduce (same order as r6) ----
    double acc = 0.0;
#pragma unroll
    for (int k = 0; k < NBLK / 256; ++k) acc += myv[k];
    __syncthreads();            // everyone past sum-phase use of red[]
    red[tid] = acc;
    __syncthreads();
    for (int s = 128; s > 0; s >>= 1) {
        if (tid < s) red[tid] += red[tid + s];
        __syncthreads();
    }
    if (tid == 0) {
        float S = (float)red[0];
        norm_sh = __fadd_rn(__fmul_rn(S, DXf), 1e-8f);
    }
    __syncthreads();
    float norm = norm_sh;

    // ---- phase C: per-candidate score AND precomputed next position ----
    float s_val = 0.0f;
    int nxt = -2;   // sentinel: no precomputed next
    if (tid < NCAND && myc > 0 && myc < GRID_N - 1) {
        float a0 = fixv(lo.x), b0 = fixv(lo.y);
        float a1 = fixv(hi.x), b1 = fixv(hi.y);
        float p1 = fmaxf(__fdiv_rn(raw_prob(a1, b1), norm), 1e-12f);
        float p0 = fmaxf(__fdiv_rn(raw_prob(a0, b0), norm), 1e-12f);
        s_val = __fdiv_rn(__fsub_rn(logf(p1), logf(p0)), TWODXf);
        // candidate tid is occupied at step (tid>>1)+1 (boundary-origin) or 0 (c0)
        int nidx = (tid == NCAND - 1) ? 0 : (tid >> 1) + 1;
        if (nidx < N_STEPS) {
            float n = noise[nidx];
            // exact walk-step fp sequence with s = s_val:
            float move = __fadd_rn(__fmul_rn(s_val, DTf), __fmul_rn(n, SQ2DTf));
            if (!isfinite(move)) move = 0.0f;
            int shift = host_f2i(__fdiv_rn(move, DXf));
            nxt = wrap_clip(myc, shift);
        }
    }
    cand_c[tid] = (tid < NCAND) ? myc : -1;
    cand_next[tid] = nxt;
    __syncthreads();

    if (tid != 0) return;

    // ---- phase D: sequential walk via transition table ----
    int c = cand_c[NCAND - 1];   // == *c0p
    int ci = NCAND - 1;          // candidate id of current position (-1 = unknown)
    int t = 0;
    while (t < N_STEPS) {
        if (c <= 0 || c >= GRID_N - 1) {
            // boundary: s==0; landing position is candidate 2t+parity by construction
            int j = 2 * t + ((c != 0) ? 1 : 0);
            c = cand_c[j];
            ci = j;
            ++t;
        } else {
            int nx = (ci >= 0) ? cand_next[ci] : -2;
            if (nx != -2) {
                c = nx;        // precomputed with bit-identical fp ops
                ci = -1;
                ++t;
            } else {
                // rare fallback: interior position not in table -> global loads
                float a1v = fixv(psi[2 * (c + 1)]);
                float b1v = fixv(psi[2 * (c + 1) + 1]);
                float a0v = fixv(psi[2 * (c - 1)]);
                float b0v = fixv(psi[2 * (c - 1) + 1]);
                float p1 = fmaxf(__fdiv_rn(raw_prob(a1v, b1v), norm), 1e-12f);
                float p0 = fmaxf(__fdiv_rn(raw_prob(a0v, b0v), norm), 1e-12f);
                float s = __fdiv_rn(__fsub_rn(logf(p1), logf(p0)), TWODXf);
                float n = noise[t];
                float move = __fadd_rn(__fmul_rn(s, DTf), __fmul_rn(n, SQ2DTf));
                if (!isfinite(move)) move = 0.0f;
                int shift = host_f2i(__fdiv_rn(move, DXf));
                c = wrap_clip(c, shift);
                ci = -1;
                ++t;
            }
        }
    }
    out[0] = x[c];
}

extern "C" void kernel_launch(void* const* d_in, const int* in_sizes, int n_in,
                              void* d_out, int out_size, void* d_ws, size_t ws_size,
                              hipStream_t stream) {
    const float* psi   = (const float*)d_in[0];
    const float* noise = (const float*)d_in[1];
    const float* x     = (const float*)d_in[2];
    const int*   c0    = (const int*)d_in[3];
    float* out = (float*)d_out;

    unsigned long long* partials_u = (unsigned long long*)d_ws;

    // sentinel-init partials each call (graph-safe memset node)
    hipMemsetAsync(d_ws, 0xFF, NBLK * sizeof(unsigned long long), stream);
    qpe_fused3_kernel<<<NBLK, THREADS, 0, stream>>>(psi, noise, x, c0,
                                                    partials_u, out);
}

// Round 8
// 34.729 us; speedup vs baseline: 1.2692x; 1.2692x over previous
//
#include <hip/hip_runtime.h>
#include <cstdint>
#include <climits>

#define GRID_N 16777216
#define GMAX (GRID_N - 1)
#define N_STEPS 100
#define NCAND (2 * N_STEPS + 1)   // 200 boundary-origin candidates + c0
#define NNODE (2 * N_STEPS)       // boundary-state nodes (t,b), t in [0,100)
#define NLEV 8                    // 2^7 = 128 >= 100 transitions
#define NBLK 2048
#define THREADS 256
#define TTOT (NBLK * THREADS)     // 524288 threads; GRID_N/2 = 16*TTOT float4s

#define TERM_FLAG 0x40000000      // terminal: t==100, low 24 bits = final c
#define FALLBACK  (-1)

// nan_to_num(psi, nan=0.0, posinf=1.0, neginf=-1.0)
__device__ __forceinline__ float fixv(float v) {
    if (isnan(v)) return 0.0f;
    if (isinf(v)) return v > 0.0f ? 1.0f : -1.0f;
    return v;
}

// psi0*psi0 + psi1*psi1 in strict f32, no FMA contraction (match host semantics)
__device__ __forceinline__ float raw_prob(float a, float b) {
    return __fadd_rn(__fmul_rn(a, a), __fmul_rn(b, b));
}

// x86 cvttss2si semantics: out-of-range or NaN -> INT_MIN (NOT GPU saturation)
__device__ __forceinline__ int host_f2i(float sf) {
    if (!(sf >= -2147483648.0f && sf < 2147483648.0f)) return INT_MIN;
    return (int)sf;
}

__device__ __forceinline__ int wrap_clip(int c, int shift) {
    int r = (int)((unsigned)c + (unsigned)shift);  // int32 wrapping add (XLA/NumPy)
    if (r < 0) r = 0;
    if (r > GMAX) r = GMAX;
    return r;
}

__device__ __forceinline__ double pair_prob(float4 v) {
    return (double)raw_prob(fixv(v.x), fixv(v.y)) +
           (double)raw_prob(fixv(v.z), fixv(v.w));
}

__global__ __launch_bounds__(256) void qpe_sum_kernel(const float4* __restrict__ psi4,
                                                      double* __restrict__ partials) {
    const int tid = threadIdx.x;
    int i = blockIdx.x * THREADS + tid;
    double a0 = 0.0, a1 = 0.0, a2 = 0.0, a3 = 0.0;
#pragma unroll
    for (int k = 0; k < 4; ++k) {
        // 4 independent loads in flight per iteration (ILP for BW saturation)
        float4 v0 = psi4[i];
        float4 v1 = psi4[i + TTOT];
        float4 v2 = psi4[i + 2 * TTOT];
        float4 v3 = psi4[i + 3 * TTOT];
        i += 4 * TTOT;
        a0 += pair_prob(v0);
        a1 += pair_prob(v1);
        a2 += pair_prob(v2);
        a3 += pair_prob(v3);
    }
    double acc = (a0 + a1) + (a2 + a3);
    __shared__ double sm[256];
    sm[tid] = acc;
    __syncthreads();
    for (int s = 128; s > 0; s >>= 1) {   // fixed-order tree -> deterministic
        if (tid < s) sm[tid] += sm[tid + s];
        __syncthreads();
    }
    if (tid == 0) partials[blockIdx.x] = sm[0];
}

__global__ __launch_bounds__(256) void qpe_walk_kernel(const float* __restrict__ psi,
                                                       const float* __restrict__ noise,
                                                       const float* __restrict__ x,
                                                       const int* __restrict__ c0p,
                                                       const double* __restrict__ partials,
                                                       float* __restrict__ out) {
    const int tid = threadIdx.x;
    const float DXf    = (float)(20.0 / (double)(GRID_N - 1));
    const float TWODXf = (float)(2.0 * (20.0 / (double)(GRID_N - 1)));
    const float DTf    = 0.01f;
    const float SQ2DTf = (float)0.14142135623730950488;  // np.sqrt(0.02) -> f32

    __shared__ int    cand_c[256];
    __shared__ int    cand_next[256];
    __shared__ int    lift[NLEV][NNODE];
    __shared__ double red[256];
    __shared__ float  norm_sh;

    // ---- phase A: candidate positions; issue psi loads immediately ----
    // From a boundary b at step t (score==0 there), the next index is
    //   clip(wrap(b, int((noise[t]*sqrt2dt)/DX)))  -- a function of noise only.
    // tid = 2t + parity (parity 1 -> b = GMAX); tid NCAND-1 -> c0 itself.
    int myc = -1;
    float2 lo = make_float2(0.0f, 0.0f), hi = make_float2(0.0f, 0.0f);
    if (tid < NCAND) {
        if (tid == NCAND - 1) {
            myc = *c0p;
        } else {
            int t = tid >> 1;
            float n = noise[t];
            // identical fp sequence to a walk step with s==0:
            float move = __fadd_rn(__fmul_rn(0.0f, DTf), __fmul_rn(n, SQ2DTf));
            if (!isfinite(move)) move = 0.0f;
            int shift = host_f2i(__fdiv_rn(move, DXf));
            int b = (tid & 1) ? GMAX : 0;
            myc = wrap_clip(b, shift);
        }
        if (myc > 0 && myc < GMAX) {
            lo = *(const float2*)(psi + 2 * myc - 2);  // psi[c-1][0..1]
            hi = *(const float2*)(psi + 2 * myc + 2);  // psi[c+1][0..1]
        }
        // pin: issue now so latency hides under phase B
        asm volatile("" : "+v"(lo.x), "+v"(lo.y), "+v"(hi.x), "+v"(hi.y));
    }

    // ---- phase B: deterministic fixed-order f64 reduce of partials ----
    double acc = 0.0;
#pragma unroll
    for (int k = 0; k < NBLK / 256; ++k) acc += partials[tid + k * 256];
    red[tid] = acc;
    __syncthreads();
    for (int s = 128; s > 0; s >>= 1) {
        if (tid < s) red[tid] += red[tid + s];
        __syncthreads();
    }
    if (tid == 0) {
        float S = (float)red[0];
        norm_sh = __fadd_rn(__fmul_rn(S, DXf), 1e-8f);
    }
    __syncthreads();
    float norm = norm_sh;

    // ---- phase C: per-candidate score AND precomputed next position ----
    float s_val = 0.0f;
    int nxt = -2;   // sentinel: no precomputed next
    if (tid < NCAND && myc > 0 && myc < GMAX) {
        float a0 = fixv(lo.x), b0 = fixv(lo.y);
        float a1 = fixv(hi.x), b1 = fixv(hi.y);
        float p1 = fmaxf(__fdiv_rn(raw_prob(a1, b1), norm), 1e-12f);
        float p0 = fmaxf(__fdiv_rn(raw_prob(a0, b0), norm), 1e-12f);
        s_val = __fdiv_rn(__fsub_rn(logf(p1), logf(p0)), TWODXf);
        // candidate tid is occupied at step (tid>>1)+1 (boundary-origin) or 0 (c0)
        int nidx = (tid == NCAND - 1) ? 0 : (tid >> 1) + 1;
        if (nidx < N_STEPS) {
            float n = noise[nidx];
            // exact walk-step fp sequence with s = s_val:
            float move = __fadd_rn(__fmul_rn(s_val, DTf), __fmul_rn(n, SQ2DTf));
            if (!isfinite(move)) move = 0.0f;
            int shift = host_f2i(__fdiv_rn(move, DXf));
            nxt = wrap_clip(myc, shift);
        }
    }
    cand_c[tid] = (tid < NCAND) ? myc : -1;
    cand_next[tid] = nxt;
    // warm x[] at possible final positions (prefetch; values discarded)
    if (tid < NCAND) {
        float w = x[myc < 0 ? 0 : myc];
        float w2 = x[(nxt < 0) ? 0 : nxt];
        asm volatile("" :: "v"(w), "v"(w2));
    }
    __syncthreads();

    // ---- phase L0: level-0 transitions for boundary nodes (t,b), n = 2t+b ----
    if (tid < NNODE) {
        int t = tid >> 1;
        int v;
        int c1 = cand_c[tid];                    // landing after step t (exact)
        if (c1 == 0 || c1 == GMAX) {
            int t1 = t + 1;
            v = (t1 == N_STEPS) ? (TERM_FLAG | c1) : ((t1 << 1) | (c1 == GMAX));
        } else if (t + 1 == N_STEPS) {
            v = TERM_FLAG | c1;                  // interior final at t=100
        } else {
            int c2 = cand_next[tid];             // position after step t+1 (exact)
            if (c2 == 0 || c2 == GMAX) {
                int t2 = t + 2;
                v = (t2 == N_STEPS) ? (TERM_FLAG | c2) : ((t2 << 1) | (c2 == GMAX));
            } else if (t + 2 == N_STEPS) {
                v = TERM_FLAG | c2;              // interior final at t=100
            } else {
                v = FALLBACK;                    // interior non-candidate mid-walk
            }
        }
        lift[0][tid] = v;
    }
    __syncthreads();
    // ---- doubling levels: lift[k][n] = lift[k-1] applied twice (saturating) ----
#pragma unroll
    for (int k = 1; k < NLEV; ++k) {
        if (tid < NNODE) {
            int v = lift[k - 1][tid];
            lift[k][tid] = (v >= 0 && v < TERM_FLAG) ? lift[k - 1][v] : v;
        }
        __syncthreads();
    }

    if (tid != 0) return;

    // ---- phase D: traverse ----
    int c = cand_c[NCAND - 1];   // == *c0p
    int t = 0;
    bool need_serial = false;

    // step 0 from c0 (interior in this problem; handle boundary anyway)
    int node;
    if (c == 0 || c == GMAX) {
        node = (0 << 1) | (c == GMAX);
    } else {
        int n1 = cand_next[NCAND - 1];           // position after step 0 (exact)
        if (n1 == -2) { need_serial = true; node = -1; }
        else if (n1 == 0 || n1 == GMAX) {
            if (N_STEPS == 1) { out[0] = x[n1]; return; }
            node = (1 << 1) | (n1 == GMAX);
        } else if (N_STEPS == 1) {
            out[0] = x[n1]; return;
        } else {
            need_serial = true; t = 1; c = n1; node = -1;   // rare
        }
    }

    if (!need_serial) {
        // binary lifting: highest level covers 128 >= 100 transitions, so one
        // application usually terminates; descend on fallback-blocked levels.
        for (int guard = 0; guard < 64; ++guard) {
            if (node >= TERM_FLAG) break;        // shouldn't happen here
            int applied = 0;
            for (int k = NLEV - 1; k >= 0; --k) {
                int v = lift[k][node];
                if (v != FALLBACK) {
                    node = v;
                    applied = 1;
                    break;
                }
            }
            if (!applied) {                       // lift[0][node] == FALLBACK
                t = node >> 1;
                c = (node & 1) ? GMAX : 0;
                need_serial = true;
                break;
            }
            if (node >= TERM_FLAG) break;
        }
        if (!need_serial && node >= TERM_FLAG) {
            out[0] = x[node & 0xFFFFFF];
            return;
        }
    }

    // ---- serial fallback from exact state (t, c): r6 loop, unconditional ----
    while (t < N_STEPS) {
        if (c <= 0 || c >= GMAX) {
            int j = 2 * t + ((c != 0) ? 1 : 0);
            c = cand_c[j];                        // exact landing (phase A)
            ++t;
        } else {
            float a1v = fixv(psi[2 * (c + 1)]);
            float b1v = fixv(psi[2 * (c + 1) + 1]);
            float a0v = fixv(psi[2 * (c - 1)]);
            float b0v = fixv(psi[2 * (c - 1) + 1]);
            float p1 = fmaxf(__fdiv_rn(raw_prob(a1v, b1v), norm), 1e-12f);
            float p0 = fmaxf(__fdiv_rn(raw_prob(a0v, b0v), norm), 1e-12f);
            float s = __fdiv_rn(__fsub_rn(logf(p1), logf(p0)), TWODXf);
            float n = noise[t];
            float move = __fadd_rn(__fmul_rn(s, DTf), __fmul_rn(n, SQ2DTf));
            if (!isfinite(move)) move = 0.0f;
            int shift = host_f2i(__fdiv_rn(move, DXf));
            c = wrap_clip(c, shift);
            ++t;
        }
    }
    out[0] = x[c];
}

extern "C" void kernel_launch(void* const* d_in, const int* in_sizes, int n_in,
                              void* d_out, int out_size, void* d_ws, size_t ws_size,
                              hipStream_t stream) {
    const float* psi   = (const float*)d_in[0];
    const float* noise = (const float*)d_in[1];
    const float* x     = (const float*)d_in[2];
    const int*   c0    = (const int*)d_in[3];
    float* out = (float*)d_out;

    double* partials = (double*)d_ws;

    qpe_sum_kernel<<<NBLK, THREADS, 0, stream>>>((const float4*)psi, partials);
    qpe_walk_kernel<<<1, THREADS, 0, stream>>>(psi, noise, x, c0, partials, out);
}